// Round 6
// baseline (839.563 us; speedup 1.0000x reference)
//
#include <hip/hip_runtime.h>
#include <hip/hip_cooperative_groups.h>
#include <math.h>

namespace cg = cooperative_groups;

// ---------------- problem constants ----------------
#define BB 8
#define NN 64
#define F_IN 32
#define F_E 16
#define HH 64        // hidden_state_size H
#define MM 64        // message size M
#define EHD 50       // edge hidden dim
#define TT 12        // l_target
#define RD 200       // readout hidden
#define NL 3

#define KP 52                 // padded edge-MLP hidden rows: 50 real + 1 bias + 1 zero
#define WROWS (KP * MM)       // 3328 rows of Waug[(k,m)][h]
#define RLEN (NN * KP)        // 3328
#define NODES (BB * NN)       // 512
#define IG 32                 // i-pair groups per batch (2 i's each)

#define NTHR 256
#define NBLK 256              // cooperative grid: 1 block/CU guaranteed resident

// ---------------- workspace layout (floats) ----------------
#define OFF_WAUG  0
#define SZ_WAUG   (WROWS * HH)                 // 212992
#define OFF_H0    (OFF_WAUG + SZ_WAUG)
#define OFF_H     (OFF_H0 + NODES * HH)
#define OFF_VALID (OFF_H + NODES * HH)
#define OFF_UG    (OFF_VALID + NODES)
#define SZ_UG     (NODES * RLEN)               // 1703936
#define OFF_C     (OFF_UG + SZ_UG)
#define SZ_C      (NODES * WROWS)              // 1703936
#define OFF_MPART (OFF_C + SZ_C)
#define SZ_MPART  (BB * IG * NN * MM)          // 1048576  [b][ig][j][m]

#define PREP_ELEMS (SZ_WAUG + NODES * HH + NODES + BB * TT)

// ============================================================
// shared phase bodies (used by both the cooperative mega kernel and
// the fallback kernel chain -> identical math on both paths)
// ============================================================
__device__ __forceinline__ void do_prep(int idx0, int stride,
    const float* __restrict__ h_in, const float* __restrict__ We2,
    const float* __restrict__ be2, float* __restrict__ ws, float* __restrict__ out)
{
    float* Waug  = ws + OFF_WAUG;
    float* h0    = ws + OFF_H0;
    float* h     = ws + OFF_H;
    float* valid = ws + OFF_VALID;
    for (int idx = idx0; idx < PREP_ELEMS; idx += stride) {
        if (idx < SZ_WAUG) {
            int km = idx >> 6, hv = idx & 63;
            int k = km >> 6, m = km & 63;
            float v = 0.0f;
            if (k < EHD)       v = We2[k * (MM * HH) + m * HH + hv];
            else if (k == EHD) v = be2[m * HH + hv];
            Waug[idx] = v;
        } else if (idx < SZ_WAUG + NODES * HH) {
            int t = idx - SZ_WAUG;
            int n = t >> 6, hv = t & 63;
            float v = (hv < F_IN) ? h_in[n * F_IN + hv] : 0.0f;
            h0[t] = v;
            h[t]  = v;
        } else if (idx < SZ_WAUG + NODES * HH + NODES) {
            int n = idx - SZ_WAUG - NODES * HH;
            float s = 0.0f;
            for (int c = 0; c < F_IN; ++c) s += h_in[n * F_IN + c];
            valid[n] = (s > 0.0f) ? 1.0f : 0.0f;
        } else {
            out[idx - (SZ_WAUG + NODES * HH + NODES)] = 0.0f;
        }
    }
}

__device__ __forceinline__ void do_edge(int eid,
    const float* __restrict__ g, const float* __restrict__ e,
    const float* __restrict__ w1, const float* __restrict__ b1,
    float* __restrict__ ws)
{
    int i = eid & 63;
    int j = (eid >> 6) & 63;
    int b = eid >> 12;

    const float* ep = e + ((size_t)((b * NN + i) * NN + j)) * F_E;
    float ev[F_E];
#pragma unroll
    for (int c = 0; c < F_E; c += 4) {
        float4 v = *(const float4*)(ep + c);
        ev[c] = v.x; ev[c + 1] = v.y; ev[c + 2] = v.z; ev[c + 3] = v.w;
    }
    float gv = g[(b * NN + i) * NN + j];

    float acc[EHD];
#pragma unroll
    for (int k = 0; k < EHD; ++k) acc[k] = b1[k];
#pragma unroll
    for (int c = 0; c < F_E; ++c) {
        float evc = ev[c];
#pragma unroll
        for (int k = 0; k < EHD; ++k) acc[k] += evc * w1[c * EHD + k];
    }
    float* ugp = ws + OFF_UG + ((size_t)(b * NN + j) * NN + i) * KP;
#pragma unroll
    for (int k = 0; k < EHD; ++k) ugp[k] = gv * fmaxf(acc[k], 0.0f);
    ugp[EHD]     = gv;   // bias row of Waug (be2 term), weighted by g
    ugp[EHD + 1] = 0.0f; // zero pad row
}

// one 32-node x 128-row tile of C[node][(k,m)] = sum_h h[node][h]*Waug[(k,m)][h]
__device__ __forceinline__ void do_cgemm_tile(int kt, int nt, int tid,
    float* __restrict__ lds, float* __restrict__ ws)
{
    const float* h    = ws + OFF_H;
    const float* Waug = ws + OFF_WAUG;
    float* C          = ws + OFF_C;
    float* hs  = lds;          // [32][64]
    float* wsh = lds + 2048;   // [128][64] float4-slot swizzled

    {
        const float4* src = (const float4*)(h + nt * 32 * HH);
        float4* dst = (float4*)hs;
#pragma unroll
        for (int q = 0; q < 2; ++q) dst[tid + q * 256] = src[tid + q * 256];
    }
    {
        const float4* src = (const float4*)(Waug + (size_t)kt * 128 * HH);
        float4* dst = (float4*)wsh;
#pragma unroll
        for (int q = 0; q < 8; ++q) {
            int fi = tid + q * 256;
            int row = fi >> 4, slot = fi & 15;
            dst[(row << 4) | (slot ^ (row & 15))] = src[fi];
        }
    }
    __syncthreads();

    int cgl = tid & 31;
    int rg  = tid >> 5;
    float acc[4][4];
#pragma unroll
    for (int q = 0; q < 4; ++q)
#pragma unroll
        for (int p = 0; p < 4; ++p) acc[q][p] = 0.0f;

#pragma unroll
    for (int hv = 0; hv < HH; hv += 4) {
        int slot = hv >> 2;
        float4 a[4], w[4];
#pragma unroll
        for (int q = 0; q < 4; ++q)
            a[q] = *(const float4*)(hs + (rg * 4 + q) * HH + hv);
#pragma unroll
        for (int p = 0; p < 4; ++p) {
            int row = cgl + 32 * p;
            w[p] = ((const float4*)wsh)[(row << 4) | (slot ^ (row & 15))];
        }
#pragma unroll
        for (int q = 0; q < 4; ++q)
#pragma unroll
            for (int p = 0; p < 4; ++p)
                acc[q][p] += a[q].x * w[p].x + a[q].y * w[p].y +
                             a[q].z * w[p].z + a[q].w * w[p].w;
    }
    __syncthreads();   // LDS reads done before caller re-stages

#pragma unroll
    for (int q = 0; q < 4; ++q) {
        int node = nt * 32 + rg * 4 + q;
#pragma unroll
        for (int p = 0; p < 4; ++p) {
            int km = kt * 128 + cgl + 32 * p;
            C[(size_t)node * WROWS + km] = acc[q][p];
        }
    }
}

// message partial for i-pair {2ig, 2ig+1}:
// m_part[b][ig][j][m] = sum_{ii,k} ug[b,j,i,k] * C[(b,i)][(k,m)]
__device__ __forceinline__ void do_msg_pair(int b, int ig, int tid,
    float* __restrict__ lds, float* __restrict__ ws)
{
    float* C_s  = lds;          // [52][64]
    float* ug_t = lds + 3328;   // [52][64]  [k][j]

    int tx = tid & 15;   // m-group
    int ty = tid >> 4;   // j-group
    float acc[4][4];
#pragma unroll
    for (int q = 0; q < 4; ++q)
#pragma unroll
        for (int p = 0; p < 4; ++p) acc[q][p] = 0.0f;

    for (int ii = 0; ii < 2; ++ii) {
        int i = ig * 2 + ii;
        const float* Cg  = ws + OFF_C  + (size_t)(b * NN + i) * WROWS;
        const float* ugg = ws + OFF_UG + (size_t)(b * NN) * RLEN + i * KP;
        {
            const float4* src = (const float4*)Cg;
            float4* dst = (float4*)C_s;
            for (int f = tid; f < 832; f += NTHR) dst[f] = src[f];
        }
        for (int f = tid; f < 832; f += NTHR) {
            int j = f / 13, kq = f - j * 13;
            float4 v = *(const float4*)(ugg + (size_t)j * RLEN + kq * 4);
            ug_t[(kq * 4 + 0) * 64 + j] = v.x;
            ug_t[(kq * 4 + 1) * 64 + j] = v.y;
            ug_t[(kq * 4 + 2) * 64 + j] = v.z;
            ug_t[(kq * 4 + 3) * 64 + j] = v.w;
        }
        __syncthreads();

        const float4* C4 = (const float4*)C_s;
#pragma unroll 4
        for (int k = 0; k < KP; ++k) {
            float4 bv = C4[k * 16 + tx];
            float4 av = *(const float4*)(ug_t + k * 64 + ty * 4);
            acc[0][0] += av.x * bv.x; acc[0][1] += av.x * bv.y; acc[0][2] += av.x * bv.z; acc[0][3] += av.x * bv.w;
            acc[1][0] += av.y * bv.x; acc[1][1] += av.y * bv.y; acc[1][2] += av.y * bv.z; acc[1][3] += av.y * bv.w;
            acc[2][0] += av.z * bv.x; acc[2][1] += av.z * bv.y; acc[2][2] += av.z * bv.z; acc[2][3] += av.z * bv.w;
            acc[3][0] += av.w * bv.x; acc[3][1] += av.w * bv.y; acc[3][2] += av.w * bv.z; acc[3][3] += av.w * bv.w;
        }
        __syncthreads();
    }

    float* mp = ws + OFF_MPART + (size_t)(b * IG + ig) * (NN * MM);
#pragma unroll
    for (int q = 0; q < 4; ++q) {
        float4 o; o.x = acc[q][0]; o.y = acc[q][1]; o.z = acc[q][2]; o.w = acc[q][3];
        *(float4*)(mp + (size_t)(ty * 4 + q) * MM + tx * 4) = o;
    }
}

// reduce 32 partials for one node + GRU cell; needs lds[768]
__device__ __forceinline__ void do_gru(int node, int tid,
    float* __restrict__ lds, float* __restrict__ ws,
    const float* __restrict__ W_ih, const float* __restrict__ W_hh,
    const float* __restrict__ b_ih, const float* __restrict__ b_hh)
{
    int b = node >> 6, j = node & 63;
    float* mpart = lds;         // [4][64]
    float* mv    = lds + 256;
    float* hvs   = lds + 320;
    float* gi_s  = lds + 384;   // [192]
    float* gh_s  = lds + 576;   // [192]
    float* h           = ws + OFF_H;
    const float* valid = ws + OFF_VALID;

    int lane = tid & 63, w = tid >> 6;
    if (tid < HH) hvs[tid] = h[(size_t)node * HH + tid];

    float s = 0.0f;
#pragma unroll
    for (int q = 0; q < 8; ++q) {
        int ig = w * 8 + q;
        s += ws[OFF_MPART + ((size_t)(b * IG + ig) * NN + j) * MM + lane];
    }
    mpart[w * 64 + lane] = s;
    __syncthreads();

    if (tid < MM)
        mv[tid] = mpart[tid] + mpart[64 + tid] + mpart[128 + tid] + mpart[192 + tid];
    __syncthreads();

    if (tid < 3 * HH) {
        int x = tid;
        float gi = b_ih[x], gh = b_hh[x];
        const float4* wi = (const float4*)(W_ih + x * MM);
        const float4* wh = (const float4*)(W_hh + x * HH);
#pragma unroll
        for (int c = 0; c < HH / 4; ++c) {
            float4 aw = wi[c], bw = wh[c];
            gi += aw.x * mv[c * 4] + aw.y * mv[c * 4 + 1] + aw.z * mv[c * 4 + 2] + aw.w * mv[c * 4 + 3];
            gh += bw.x * hvs[c * 4] + bw.y * hvs[c * 4 + 1] + bw.z * hvs[c * 4 + 2] + bw.w * hvs[c * 4 + 3];
        }
        gi_s[x] = gi;
        gh_s[x] = gh;
    }
    __syncthreads();

    if (tid < HH) {
        float r = 1.0f / (1.0f + expf(-(gi_s[tid] + gh_s[tid])));
        float z = 1.0f / (1.0f + expf(-(gi_s[HH + tid] + gh_s[HH + tid])));
        float n = tanhf(gi_s[2 * HH + tid] + r * gh_s[2 * HH + tid]);
        float hn = (1.0f - z) * n + z * hvs[tid];
        h[(size_t)node * HH + tid] = hn * valid[node];
    }
    __syncthreads();   // safe LDS reuse on next call
}

// readout for one node; needs lds[528]
__device__ __forceinline__ void do_readout(int node, int tid,
    float* __restrict__ lds, float* __restrict__ ws,
    const float* __restrict__ Wi1, const float* __restrict__ bi1,
    const float* __restrict__ Wi2, const float* __restrict__ bi2,
    const float* __restrict__ Wj1, const float* __restrict__ bj1,
    const float* __restrict__ Wj2, const float* __restrict__ bj2,
    float* __restrict__ out)
{
    float* cat = lds;          // [128]
    float* ih  = lds + 128;    // [200]
    float* jh  = lds + 328;    // [200]
    const float* h     = ws + OFF_H;
    const float* h0    = ws + OFF_H0;
    const float* valid = ws + OFF_VALID;
    int b = node >> 6;

    if (tid < 2 * HH)
        cat[tid] = (tid < HH) ? h[(size_t)node * HH + tid]
                              : h0[(size_t)node * HH + (tid - HH)];
    __syncthreads();

    if (tid < RD) {
        float a = bi1[tid];
        for (int c = 0; c < 2 * HH; ++c) a += cat[c] * Wi1[c * RD + tid];
        ih[tid] = fmaxf(a, 0.0f);
        float bj = bj1[tid];
        for (int c = 0; c < HH; ++c) bj += cat[c] * Wj1[c * RD + tid];
        jh[tid] = fmaxf(bj, 0.0f);
    }
    __syncthreads();

    if (tid < TT) {
        float i2 = bi2[tid], j2 = bj2[tid];
        for (int u = 0; u < RD; ++u) {
            i2 += ih[u] * Wi2[u * TT + tid];
            j2 += jh[u] * Wj2[u * TT + tid];
        }
        float sig = 1.0f / (1.0f + expf(-i2));
        atomicAdd(&out[b * TT + tid], valid[node] * sig * j2);
    }
    __syncthreads();   // safe LDS reuse on next call
}

// ============================================================
// cooperative mega kernel: 256 blocks (1/CU guaranteed resident)
// ============================================================
__global__ __launch_bounds__(NTHR) void mega_kernel(
    const float* __restrict__ g,   const float* __restrict__ h_in,
    const float* __restrict__ e,
    const float* __restrict__ We1, const float* __restrict__ be1,
    const float* __restrict__ We2, const float* __restrict__ be2,
    const float* __restrict__ W_ih, const float* __restrict__ W_hh,
    const float* __restrict__ b_ih, const float* __restrict__ b_hh,
    const float* __restrict__ Wi1, const float* __restrict__ bi1,
    const float* __restrict__ Wi2, const float* __restrict__ bi2,
    const float* __restrict__ Wj1, const float* __restrict__ bj1,
    const float* __restrict__ Wj2, const float* __restrict__ bj2,
    float* __restrict__ ws, float* __restrict__ out)
{
    cg::grid_group grid = cg::this_grid();
    __shared__ float lds[10240];   // 40 KB, aliased per phase

    const int blk = blockIdx.x;
    const int tid = threadIdx.x;

    // P0: prep (blocks 0..127, grid-stride) + edge MLP (blocks 128..255)
    if (blk < 128) {
        do_prep(blk * NTHR + tid, 128 * NTHR, h_in, We2, be2, ws, out);
    } else {
        float* w1 = lds;               // [16][50]
        float* b1 = lds + F_E * EHD;
        for (int t = tid; t < F_E * EHD; t += NTHR) w1[t] = We1[t];
        if (tid < EHD) b1[tid] = be1[tid];
        __syncthreads();
        do_edge((blk - 128) * NTHR + tid, g, e, w1, b1, ws);
    }
    __threadfence(); grid.sync();

    for (int l = 0; l < NL; ++l) {
        // P1: C GEMM, 416 tiles over 256 blocks
        for (int t = blk; t < 416; t += NBLK)
            do_cgemm_tile(t % 26, t / 26, tid, lds, ws);
        __threadfence(); grid.sync();

        // P2: msg partial GEMM, 256 i-pair blocks
        do_msg_pair(blk >> 5, blk & 31, tid, lds, ws);
        __threadfence(); grid.sync();

        // P3: reduce + GRU, 512 nodes over 256 blocks
        for (int n = blk; n < NODES; n += NBLK)
            do_gru(n, tid, lds, ws, W_ih, W_hh, b_ih, b_hh);
        __threadfence(); grid.sync();
    }

    // P4: readout, 512 nodes over 256 blocks
    for (int n = blk; n < NODES; n += NBLK)
        do_readout(n, tid, lds, ws, Wi1, bi1, Wi2, bi2, Wj1, bj1, Wj2, bj2, out);
}

// ============================================================
// fallback kernel chain (round-2 structure; same device functions)
// ============================================================
__global__ __launch_bounds__(NTHR) void k_prep(const float* __restrict__ h_in,
    const float* __restrict__ We2, const float* __restrict__ be2,
    float* __restrict__ ws, float* __restrict__ out)
{
    do_prep(blockIdx.x * NTHR + threadIdx.x, gridDim.x * NTHR, h_in, We2, be2, ws, out);
}

__global__ __launch_bounds__(NTHR) void k_edge(const float* __restrict__ g,
    const float* __restrict__ e, const float* __restrict__ We1,
    const float* __restrict__ be1, float* __restrict__ ws)
{
    __shared__ float lds[F_E * EHD + EHD];
    float* w1 = lds;
    float* b1 = lds + F_E * EHD;
    for (int t = threadIdx.x; t < F_E * EHD; t += NTHR) w1[t] = We1[t];
    if (threadIdx.x < EHD) b1[threadIdx.x] = be1[threadIdx.x];
    __syncthreads();
    do_edge(blockIdx.x * NTHR + threadIdx.x, g, e, w1, b1, ws);
}

__global__ __launch_bounds__(NTHR) void k_cgemm(float* __restrict__ ws)
{
    __shared__ float lds[10240];
    do_cgemm_tile(blockIdx.x % 26, blockIdx.x / 26, threadIdx.x, lds, ws);
}

__global__ __launch_bounds__(NTHR) void k_msg(float* __restrict__ ws)
{
    __shared__ float lds[6656];
    do_msg_pair(blockIdx.x >> 5, blockIdx.x & 31, threadIdx.x, lds, ws);
}

__global__ __launch_bounds__(NTHR) void k_gru(const float* __restrict__ W_ih,
    const float* __restrict__ W_hh, const float* __restrict__ b_ih,
    const float* __restrict__ b_hh, float* __restrict__ ws)
{
    __shared__ float lds[768];
    do_gru(blockIdx.x, threadIdx.x, lds, ws, W_ih, W_hh, b_ih, b_hh);
}

__global__ __launch_bounds__(NTHR) void k_readout(
    const float* __restrict__ Wi1, const float* __restrict__ bi1,
    const float* __restrict__ Wi2, const float* __restrict__ bi2,
    const float* __restrict__ Wj1, const float* __restrict__ bj1,
    const float* __restrict__ Wj2, const float* __restrict__ bj2,
    float* __restrict__ ws, float* __restrict__ out)
{
    __shared__ float lds[528];
    do_readout(blockIdx.x, threadIdx.x, lds, ws,
               Wi1, bi1, Wi2, bi2, Wj1, bj1, Wj2, bj2, out);
}

// ============================================================
extern "C" void kernel_launch(void* const* d_in, const int* in_sizes, int n_in,
                              void* d_out, int out_size, void* d_ws, size_t ws_size,
                              hipStream_t stream) {
    (void)in_sizes; (void)n_in; (void)out_size; (void)ws_size;
    const float* g    = (const float*)d_in[0];
    const float* h_in = (const float*)d_in[1];
    const float* e    = (const float*)d_in[2];
    const float* We1  = (const float*)d_in[3];
    const float* be1  = (const float*)d_in[4];
    const float* We2  = (const float*)d_in[5];
    const float* be2  = (const float*)d_in[6];
    const float* W_ih = (const float*)d_in[7];
    const float* W_hh = (const float*)d_in[8];
    const float* b_ih = (const float*)d_in[9];
    const float* b_hh = (const float*)d_in[10];
    const float* Wi1  = (const float*)d_in[11];
    const float* bi1  = (const float*)d_in[12];
    const float* Wi2  = (const float*)d_in[13];
    const float* bi2  = (const float*)d_in[14];
    const float* Wj1  = (const float*)d_in[15];
    const float* bj1  = (const float*)d_in[16];
    const float* Wj2  = (const float*)d_in[17];
    const float* bj2  = (const float*)d_in[18];
    float* out = (float*)d_out;
    float* ws  = (float*)d_ws;

    void* args[] = {
        (void*)&g, (void*)&h_in, (void*)&e,
        (void*)&We1, (void*)&be1, (void*)&We2, (void*)&be2,
        (void*)&W_ih, (void*)&W_hh, (void*)&b_ih, (void*)&b_hh,
        (void*)&Wi1, (void*)&bi1, (void*)&Wi2, (void*)&bi2,
        (void*)&Wj1, (void*)&bj1, (void*)&Wj2, (void*)&bj2,
        (void*)&ws, (void*)&out
    };
    hipError_t err = hipLaunchCooperativeKernel((void*)mega_kernel, dim3(NBLK),
                                                dim3(NTHR), args, 0, stream);
    if (err != hipSuccess) {
        // fallback: known-good multi-kernel chain (identical math)
        k_prep<<<(PREP_ELEMS + NTHR - 1) / NTHR, NTHR, 0, stream>>>(h_in, We2, be2, ws, out);
        k_edge<<<(BB * NN * NN) / NTHR, NTHR, 0, stream>>>(g, e, We1, be1, ws);
        for (int l = 0; l < NL; ++l) {
            k_cgemm<<<416, NTHR, 0, stream>>>(ws);
            k_msg<<<256, NTHR, 0, stream>>>(ws);
            k_gru<<<NODES, NTHR, 0, stream>>>(W_ih, W_hh, b_ih, b_hh, ws);
        }
        k_readout<<<NODES, NTHR, 0, stream>>>(Wi1, bi1, Wi2, bi2,
                                              Wj1, bj1, Wj2, bj2, ws, out);
    }
}

// Round 7
// 306.073 us; speedup vs baseline: 2.7430x; 2.7430x over previous
//
#include <hip/hip_runtime.h>
#include <math.h>

// ---------------- problem constants ----------------
#define BB 8
#define NN 64
#define F_IN 32
#define F_E 16
#define HH 64        // hidden_state_size H
#define MM 64        // message size M
#define EHD 50       // edge hidden dim
#define TT 12        // l_target
#define RD 200       // readout hidden
#define NL 3

#define KP 52                 // 50 real k + 1 bias row + 1 zero pad
#define NODES (BB * NN)       // 512
#define NTHR 256

// ---------------- workspace layout (floats) ----------------
// Waug: [(k,m)][h] 212992 | h0,h: [512][64] | valid | ug2: [b][k][i][j] 1703936
// T2:   [b][k][h][j] 1703936   -> total ~14.7 MB
#define OFF_WAUG  0
#define SZ_WAUG   (KP * MM * HH)
#define OFF_H0    (OFF_WAUG + SZ_WAUG)
#define OFF_H     (OFF_H0 + NODES * HH)
#define OFF_VALID (OFF_H + NODES * HH)
#define OFF_UG2   (OFF_VALID + NODES)
#define SZ_UG2    (BB * KP * NN * NN)
#define OFF_T2    (OFF_UG2 + SZ_UG2)
#define SZ_T2     (BB * KP * HH * NN)

#define PREP_ELEMS (SZ_WAUG + NODES * HH + NODES + BB * TT)

// ============================================================
// prep+edge fused: blocks 0..127 edge MLP, 128..255 prep.
// edge thread = (b, i, j) with j fastest -> all loads/stores coalesced.
// ug2[b][k][i][j] = g[b,i,j]*relu(e@We1+be1)[k]; k=50 -> g; k=51 -> 0.
// ============================================================
__global__ __launch_bounds__(NTHR) void k_prep_edge(
    const float* __restrict__ g, const float* __restrict__ h_in,
    const float* __restrict__ e,
    const float* __restrict__ We1, const float* __restrict__ be1,
    const float* __restrict__ We2, const float* __restrict__ be2,
    float* __restrict__ ws, float* __restrict__ out)
{
    const int blk = blockIdx.x;
    const int tid = threadIdx.x;

    if (blk < 128) {
        // ---- edge MLP ----
        __shared__ float w1[F_E * EHD];   // [c][k]
        __shared__ float b1[EHD];
        for (int t = tid; t < F_E * EHD; t += NTHR) w1[t] = We1[t];
        if (tid < EHD) b1[tid] = be1[tid];
        __syncthreads();

        int idx = blk * NTHR + tid;       // (b, i, j), j fastest
        int j = idx & 63;
        int i = (idx >> 6) & 63;
        int b = idx >> 12;

        const float* ep = e + ((size_t)((b * NN + i) * NN + j)) * F_E;
        float ev[F_E];
#pragma unroll
        for (int c = 0; c < F_E; c += 4) {
            float4 v = *(const float4*)(ep + c);
            ev[c] = v.x; ev[c + 1] = v.y; ev[c + 2] = v.z; ev[c + 3] = v.w;
        }
        float gv = g[(b * NN + i) * NN + j];

        float acc[EHD];
#pragma unroll
        for (int k = 0; k < EHD; ++k) acc[k] = b1[k];
#pragma unroll
        for (int c = 0; c < F_E; ++c) {
            float evc = ev[c];
#pragma unroll
            for (int k = 0; k < EHD; ++k) acc[k] += evc * w1[c * EHD + k];
        }
        float* base = ws + OFF_UG2 + (size_t)(b * KP) * (NN * NN) + i * NN + j;
#pragma unroll
        for (int k = 0; k < EHD; ++k) base[(size_t)k * (NN * NN)] = gv * fmaxf(acc[k], 0.0f);
        base[(size_t)EHD * (NN * NN)]       = gv;    // bias row (be2 via Waug)
        base[(size_t)(EHD + 1) * (NN * NN)] = 0.0f;  // zero pad row
    } else {
        // ---- prep ----
        float* Waug  = ws + OFF_WAUG;
        float* h0    = ws + OFF_H0;
        float* h     = ws + OFF_H;
        float* valid = ws + OFF_VALID;
        for (int idx = (blk - 128) * NTHR + tid; idx < PREP_ELEMS; idx += 128 * NTHR) {
            if (idx < SZ_WAUG) {
                int km = idx >> 6, hv = idx & 63;
                int k = km >> 6, m = km & 63;
                float v = 0.0f;
                if (k < EHD)       v = We2[k * (MM * HH) + m * HH + hv];
                else if (k == EHD) v = be2[m * HH + hv];
                Waug[idx] = v;
            } else if (idx < SZ_WAUG + NODES * HH) {
                int t = idx - SZ_WAUG;
                int n = t >> 6, hv = t & 63;
                float v = (hv < F_IN) ? h_in[n * F_IN + hv] : 0.0f;
                h0[t] = v;
                h[t]  = v;
            } else if (idx < SZ_WAUG + NODES * HH + NODES) {
                int n = idx - SZ_WAUG - NODES * HH;
                float s = 0.0f;
                for (int c = 0; c < F_IN; ++c) s += h_in[n * F_IN + c];
                valid[n] = (s > 0.0f) ? 1.0f : 0.0f;
            } else {
                out[idx - (SZ_WAUG + NODES * HH + NODES)] = 0.0f;
            }
        }
    }
}

// ============================================================
// step1: block (b,k) of 416. T[j,h] = sum_i ug2[b,k,i,j]*h[b,i,h]
// (64x64x64 GEMM, both operands LDS-staged, 4x4 microtile).
// Store transposed: T2[b][k][h][j] (coalesced f4 over j).
// ============================================================
__global__ __launch_bounds__(NTHR) void k_step1(float* __restrict__ ws)
{
    const int blk = blockIdx.x;            // 0..415
    const int b = blk / KP;
    const int k = blk - b * KP;
    const int tid = threadIdx.x;

    __shared__ float A_s[NN * NN];   // [i][j]  = ug2[b][k]
    __shared__ float H_s[NN * HH];   // [i][h]  = h[b]

    {
        const float4* srcA = (const float4*)(ws + OFF_UG2 + (size_t)(b * KP + k) * (NN * NN));
        const float4* srcH = (const float4*)(ws + OFF_H + (size_t)b * (NN * HH));
        float4* dA = (float4*)A_s;
        float4* dH = (float4*)H_s;
#pragma unroll
        for (int q = 0; q < 4; ++q) {
            dA[tid + q * NTHR] = srcA[tid + q * NTHR];
            dH[tid + q * NTHR] = srcH[tid + q * NTHR];
        }
    }
    __syncthreads();

    const int tx = tid & 15;   // j-f4 group
    const int ty = tid >> 4;   // h-f4 group
    float4 o0 = {0,0,0,0}, o1 = {0,0,0,0}, o2 = {0,0,0,0}, o3 = {0,0,0,0};

    const float4* A4 = (const float4*)A_s;
    const float4* H4 = (const float4*)H_s;
#pragma unroll 8
    for (int i = 0; i < NN; ++i) {
        float4 av = A4[i * 16 + tx];
        float4 hv = H4[i * 16 + ty];
        o0.x += av.x * hv.x; o0.y += av.y * hv.x; o0.z += av.z * hv.x; o0.w += av.w * hv.x;
        o1.x += av.x * hv.y; o1.y += av.y * hv.y; o1.z += av.z * hv.y; o1.w += av.w * hv.y;
        o2.x += av.x * hv.z; o2.y += av.y * hv.z; o2.z += av.z * hv.z; o2.w += av.w * hv.z;
        o3.x += av.x * hv.w; o3.y += av.y * hv.w; o3.z += av.z * hv.w; o3.w += av.w * hv.w;
    }

    float* T2 = ws + OFF_T2 + (size_t)(b * KP + k) * (HH * NN);
    *(float4*)(T2 + (4 * ty + 0) * NN + 4 * tx) = o0;
    *(float4*)(T2 + (4 * ty + 1) * NN + 4 * tx) = o1;
    *(float4*)(T2 + (4 * ty + 2) * NN + 4 * tx) = o2;
    *(float4*)(T2 + (4 * ty + 3) * NN + 4 * tx) = o3;
}

// ============================================================
// step2+GRU: block (b, jt) of 64; 8 nodes j0..j0+7.
// m[j][m] = sum_k sum_h T2[b,k,h,j] * Waug[(k*64+m)][h]
// K-loop over k with register prefetch; rotation-indexed LDS reads
// (lane-dependent h4 order) keep bank conflicts <=2-way.
// Then full GRU for the 8 nodes (no partials, no extra dispatch).
// ============================================================
__global__ __launch_bounds__(NTHR) void k_step2gru(
    const float* __restrict__ W_ih, const float* __restrict__ W_hh,
    const float* __restrict__ b_ih, const float* __restrict__ b_hh,
    float* __restrict__ ws)
{
    const int blk = blockIdx.x;        // 0..63
    const int b  = blk >> 3;
    const int j0 = (blk & 7) * 8;
    const int tid = threadIdx.x;

    __shared__ float W_s[MM * HH];     // [m][h] one k-slab of Waug (16 KB)
    __shared__ float T_s[8 * HH];      // [j][h]
    __shared__ float m_s[8 * MM];
    __shared__ float h_s[8 * HH];
    __shared__ float gi_l[8 * 3 * HH]; // [n][192]
    __shared__ float gh_l[8 * 3 * HH];

    // stage h for our 8 nodes (contiguous 512 floats)
    {
        const float4* src = (const float4*)(ws + OFF_H + (size_t)(b * NN + j0) * HH);
        if (tid < 128) ((float4*)h_s)[tid] = src[tid];
    }

    const float4* Waug4 = (const float4*)(ws + OFF_WAUG);
    const float4* T2b   = (const float4*)(ws + OFF_T2 + (size_t)(b * KP) * (HH * NN));

    const int tx = tid & 31;   // m and m+32
    const int ty = tid >> 5;   // j 0..7
    float acc0 = 0.0f, acc1 = 0.0f;

    // prefetch k=0
    float4 pw0, pw1, pw2, pw3, pt;
    {
        const float4* wk = Waug4;                  // k*1024
        pw0 = wk[tid]; pw1 = wk[tid + 256]; pw2 = wk[tid + 512]; pw3 = wk[tid + 768];
        if (tid < 128) {
            int hh = tid >> 1, jq = tid & 1;
            pt = T2b[(hh * NN + j0) / 4 + jq];     // k=0 slab
        }
    }

    for (int k = 0; k < KP; ++k) {
        // write prefetched slab to LDS
        ((float4*)W_s)[tid]       = pw0;
        ((float4*)W_s)[tid + 256] = pw1;
        ((float4*)W_s)[tid + 512] = pw2;
        ((float4*)W_s)[tid + 768] = pw3;
        if (tid < 128) {
            int hh = tid >> 1, jq = tid & 1;
            T_s[(4 * jq + 0) * HH + hh] = pt.x;
            T_s[(4 * jq + 1) * HH + hh] = pt.y;
            T_s[(4 * jq + 2) * HH + hh] = pt.z;
            T_s[(4 * jq + 3) * HH + hh] = pt.w;
        }
        __syncthreads();

        if (k < KP - 1) {  // prefetch k+1 (overlaps compute below)
            const float4* wk = Waug4 + (size_t)(k + 1) * 1024;
            pw0 = wk[tid]; pw1 = wk[tid + 256]; pw2 = wk[tid + 512]; pw3 = wk[tid + 768];
            if (tid < 128) {
                int hh = tid >> 1, jq = tid & 1;
                pt = T2b[((size_t)(k + 1) * (HH * NN) + hh * NN + j0) / 4 + jq];
            }
        }

        const float4* Ws4 = (const float4*)W_s;   // [m][16]
        const float4* Ts4 = (const float4*)T_s;   // [j][16]
#pragma unroll
        for (int s = 0; s < 16; ++s) {
            int h4 = (s + tx) & 15;                // rotation: lanes hit different banks
            float4 t4 = Ts4[ty * 16 + h4];
            float4 wa = Ws4[tx * 16 + h4];
            float4 wb = Ws4[(tx + 32) * 16 + h4];
            acc0 += t4.x * wa.x + t4.y * wa.y + t4.z * wa.z + t4.w * wa.w;
            acc1 += t4.x * wb.x + t4.y * wb.y + t4.z * wb.z + t4.w * wb.w;
        }
        __syncthreads();
    }

    m_s[ty * MM + tx]      = acc0;
    m_s[ty * MM + tx + 32] = acc1;
    __syncthreads();

    // ---- GRU gates: thread x<192 computes gate x for all 8 nodes ----
    if (tid < 3 * HH) {
        const int x = tid;
        float gi[8], gh[8];
        float bi = b_ih[x], bh = b_hh[x];
#pragma unroll
        for (int n = 0; n < 8; ++n) { gi[n] = bi; gh[n] = bh; }
        const float4* wi = (const float4*)(W_ih + x * MM);
        const float4* wh = (const float4*)(W_hh + x * HH);
        const float4* m4 = (const float4*)m_s;
        const float4* h4p = (const float4*)h_s;
#pragma unroll
        for (int c = 0; c < HH / 4; ++c) {
            float4 aw = wi[c], bw = wh[c];
#pragma unroll
            for (int n = 0; n < 8; ++n) {
                float4 mv = m4[n * 16 + c];
                float4 hv = h4p[n * 16 + c];
                gi[n] += aw.x * mv.x + aw.y * mv.y + aw.z * mv.z + aw.w * mv.w;
                gh[n] += bw.x * hv.x + bw.y * hv.y + bw.z * hv.z + bw.w * hv.w;
            }
        }
#pragma unroll
        for (int n = 0; n < 8; ++n) {
            gi_l[n * (3 * HH) + x] = gi[n];
            gh_l[n * (3 * HH) + x] = gh[n];
        }
    }
    __syncthreads();

    // ---- final update: 8 nodes x 64 dims over 2 reps ----
    float* h     = ws + OFF_H;
    const float* valid = ws + OFF_VALID;
#pragma unroll
    for (int rep = 0; rep < 2; ++rep) {
        int n = (tid >> 6) + 4 * rep;
        int t = tid & 63;
        const float* gi = gi_l + n * (3 * HH);
        const float* gh = gh_l + n * (3 * HH);
        float r = 1.0f / (1.0f + expf(-(gi[t] + gh[t])));
        float z = 1.0f / (1.0f + expf(-(gi[HH + t] + gh[HH + t])));
        float ng = tanhf(gi[2 * HH + t] + r * gh[2 * HH + t]);
        float hn = (1.0f - z) * ng + z * h_s[n * HH + t];
        int node = b * NN + j0 + n;
        h[(size_t)node * HH + t] = hn * valid[node];
    }
}

// ============================================================
// readout (verified body): 512 blocks, one node each.
// ============================================================
__global__ __launch_bounds__(NTHR) void k_readout(
    const float* __restrict__ Wi1, const float* __restrict__ bi1,
    const float* __restrict__ Wi2, const float* __restrict__ bi2,
    const float* __restrict__ Wj1, const float* __restrict__ bj1,
    const float* __restrict__ Wj2, const float* __restrict__ bj2,
    float* __restrict__ ws, float* __restrict__ out)
{
    __shared__ float cat[2 * HH];
    __shared__ float ih[RD], jh[RD];
    const float* h     = ws + OFF_H;
    const float* h0    = ws + OFF_H0;
    const float* valid = ws + OFF_VALID;
    int node = blockIdx.x, b = node >> 6, tid = threadIdx.x;

    if (tid < 2 * HH)
        cat[tid] = (tid < HH) ? h[(size_t)node * HH + tid]
                              : h0[(size_t)node * HH + (tid - HH)];
    __syncthreads();

    if (tid < RD) {
        float a = bi1[tid];
        for (int c = 0; c < 2 * HH; ++c) a += cat[c] * Wi1[c * RD + tid];
        ih[tid] = fmaxf(a, 0.0f);
        float bj = bj1[tid];
        for (int c = 0; c < HH; ++c) bj += cat[c] * Wj1[c * RD + tid];
        jh[tid] = fmaxf(bj, 0.0f);
    }
    __syncthreads();

    if (tid < TT) {
        float i2 = bi2[tid], j2 = bj2[tid];
        for (int u = 0; u < RD; ++u) {
            i2 += ih[u] * Wi2[u * TT + tid];
            j2 += jh[u] * Wj2[u * TT + tid];
        }
        float sig = 1.0f / (1.0f + expf(-i2));
        atomicAdd(&out[b * TT + tid], valid[node] * sig * j2);
    }
}

// ============================================================
extern "C" void kernel_launch(void* const* d_in, const int* in_sizes, int n_in,
                              void* d_out, int out_size, void* d_ws, size_t ws_size,
                              hipStream_t stream) {
    (void)in_sizes; (void)n_in; (void)out_size; (void)ws_size;
    const float* g    = (const float*)d_in[0];
    const float* h_in = (const float*)d_in[1];
    const float* e    = (const float*)d_in[2];
    const float* We1  = (const float*)d_in[3];
    const float* be1  = (const float*)d_in[4];
    const float* We2  = (const float*)d_in[5];
    const float* be2  = (const float*)d_in[6];
    const float* W_ih = (const float*)d_in[7];
    const float* W_hh = (const float*)d_in[8];
    const float* b_ih = (const float*)d_in[9];
    const float* b_hh = (const float*)d_in[10];
    const float* Wi1  = (const float*)d_in[11];
    const float* bi1  = (const float*)d_in[12];
    const float* Wi2  = (const float*)d_in[13];
    const float* bi2  = (const float*)d_in[14];
    const float* Wj1  = (const float*)d_in[15];
    const float* bj1  = (const float*)d_in[16];
    const float* Wj2  = (const float*)d_in[17];
    const float* bj2  = (const float*)d_in[18];
    float* out = (float*)d_out;
    float* ws  = (float*)d_ws;

    k_prep_edge<<<256, NTHR, 0, stream>>>(g, h_in, e, We1, be1, We2, be2, ws, out);
    for (int l = 0; l < NL; ++l) {
        k_step1<<<BB * KP, NTHR, 0, stream>>>(ws);
        k_step2gru<<<64, NTHR, 0, stream>>>(W_ih, W_hh, b_ih, b_hh, ws);
    }
    k_readout<<<NODES, NTHR, 0, stream>>>(Wi1, bi1, Wi2, bi2, Wj1, bj1, Wj2, bj2, ws, out);
}

// Round 14
// 237.779 us; speedup vs baseline: 3.5309x; 1.2872x over previous
//
#include <hip/hip_runtime.h>
#include <math.h>

// ---------------- problem constants ----------------
#define BB 8
#define NN 64
#define F_IN 32
#define F_E 16
#define HH 64        // hidden_state_size H
#define MM 64        // message size M
#define EHD 50       // edge hidden dim
#define TT 12        // l_target
#define RD 200       // readout hidden
#define NL 3

#define KP 52                 // 50 real k + 1 bias row + 1 zero pad
#define NODES (BB * NN)       // 512
#define NTHR 256

// ---------------- workspace layout (floats) ----------------
// WaugT: [k][h][m] 212992 | h0,h: [512][64] | valid 512 | m: [b][j][m] 32768
// ug2:   [b][k][i][j] 1703936     -> total ~8.1 MB
#define OFF_WAUGT 0
#define SZ_WAUGT  (KP * HH * MM)               // 212992
#define OFF_H0    (OFF_WAUGT + SZ_WAUGT)
#define OFF_H     (OFF_H0 + NODES * HH)
#define OFF_VALID (OFF_H + NODES * HH)
#define OFF_M     (OFF_VALID + NODES)
#define SZ_M      (BB * NN * MM)               // 32768
#define OFF_UG2   (OFF_M + SZ_M)
#define SZ_UG2    (BB * KP * NN * NN)          // 1703936

// prep covers: WaugT | h0+h | valid | out | m-zero
#define PREP_ELEMS (SZ_WAUGT + NODES * HH + NODES + BB * TT + SZ_M)

// ============================================================
// prep+edge fused: blocks 0..127 edge MLP, 128..255 prep.
// edge thread = (b, i, j) j fastest; ug2[b][k][i][j] = g*relu(e@We1+be1)[k];
// k=50 -> g (bias row via WaugT[50]=be2); k=51 -> 0.
// prep builds WaugT[k][h][m] = We2[k][m][h] transpose (layer-invariant).
// ============================================================
__global__ __launch_bounds__(NTHR) void k_prep_edge(
    const float* __restrict__ g, const float* __restrict__ h_in,
    const float* __restrict__ e,
    const float* __restrict__ We1, const float* __restrict__ be1,
    const float* __restrict__ We2, const float* __restrict__ be2,
    float* __restrict__ ws, float* __restrict__ out)
{
    const int blk = blockIdx.x;
    const int tid = threadIdx.x;

    if (blk < 128) {
        // ---- edge MLP (verified round 7) ----
        __shared__ float w1[F_E * EHD];   // [c][k]
        __shared__ float b1[EHD];
        for (int t = tid; t < F_E * EHD; t += NTHR) w1[t] = We1[t];
        if (tid < EHD) b1[tid] = be1[tid];
        __syncthreads();

        int idx = blk * NTHR + tid;       // (b, i, j), j fastest
        int j = idx & 63;
        int i = (idx >> 6) & 63;
        int b = idx >> 12;

        const float* ep = e + ((size_t)((b * NN + i) * NN + j)) * F_E;
        float ev[F_E];
#pragma unroll
        for (int c = 0; c < F_E; c += 4) {
            float4 v = *(const float4*)(ep + c);
            ev[c] = v.x; ev[c + 1] = v.y; ev[c + 2] = v.z; ev[c + 3] = v.w;
        }
        float gv = g[(b * NN + i) * NN + j];

        float acc[EHD];
#pragma unroll
        for (int k = 0; k < EHD; ++k) acc[k] = b1[k];
#pragma unroll
        for (int c = 0; c < F_E; ++c) {
            float evc = ev[c];
#pragma unroll
            for (int k = 0; k < EHD; ++k) acc[k] += evc * w1[c * EHD + k];
        }
        float* base = ws + OFF_UG2 + (size_t)(b * KP) * (NN * NN) + i * NN + j;
#pragma unroll
        for (int k = 0; k < EHD; ++k) base[(size_t)k * (NN * NN)] = gv * fmaxf(acc[k], 0.0f);
        base[(size_t)EHD * (NN * NN)]       = gv;    // bias row
        base[(size_t)(EHD + 1) * (NN * NN)] = 0.0f;  // zero pad row
    } else {
        // ---- prep ----
        float* WaugT = ws + OFF_WAUGT;
        float* h0    = ws + OFF_H0;
        float* h     = ws + OFF_H;
        float* valid = ws + OFF_VALID;
        float* m     = ws + OFF_M;
        for (int idx = (blk - 128) * NTHR + tid; idx < PREP_ELEMS; idx += 128 * NTHR) {
            if (idx < SZ_WAUGT) {
                int k = idx >> 12;
                int rem = idx & 4095;
                int hh = rem >> 6, mm = rem & 63;
                float v = 0.0f;
                if (k < EHD)       v = We2[k * (MM * HH) + mm * HH + hh];
                else if (k == EHD) v = be2[mm * HH + hh];
                WaugT[idx] = v;
            } else if (idx < SZ_WAUGT + NODES * HH) {
                int t = idx - SZ_WAUGT;
                int n = t >> 6, hv = t & 63;
                float v = (hv < F_IN) ? h_in[n * F_IN + hv] : 0.0f;
                h0[t] = v;
                h[t]  = v;
            } else if (idx < SZ_WAUGT + NODES * HH + NODES) {
                int n = idx - SZ_WAUGT - NODES * HH;
                float s = 0.0f;
                for (int c = 0; c < F_IN; ++c) s += h_in[n * F_IN + c];
                valid[n] = (s > 0.0f) ? 1.0f : 0.0f;
            } else if (idx < SZ_WAUGT + NODES * HH + NODES + BB * TT) {
                out[idx - (SZ_WAUGT + NODES * HH + NODES)] = 0.0f;
            } else {
                m[idx - (SZ_WAUGT + NODES * HH + NODES + BB * TT)] = 0.0f;
            }
        }
    }
}

// ============================================================
// fused message: block (b,k) of 416.
//  phase A: T[h][j] = sum_i ug2[b,k,i,j] * h[b,i,h]     (verified step1 microtile)
//  phase B: part[j][m] = sum_h T[h][j] * WaugT[k,h,m]
//  atomicAdd part into m[b][j][m]  (64 distinct addrs/wave -> no lane contention)
// LDS 48 KB (W_s aliases A_s after phase A) -> 3 blocks/CU by LDS.
// ============================================================
__global__ __launch_bounds__(NTHR) void k_fused_msg(float* __restrict__ ws)
{
    const int blk = blockIdx.x;            // 0..415
    const int b = blk / KP;
    const int k = blk - b * KP;
    const int tid = threadIdx.x;

    __shared__ float buf[12288];           // 48 KB
    float* A_s = buf;                      // [i][j] 4096
    float* H_s = buf + 4096;               // [i][h] 4096
    float* T_s = buf + 8192;               // [h][j] 4096
    float* W_s = buf;                      // [h][m] aliases A_s (after phase A)

    const float4* gA = (const float4*)(ws + OFF_UG2 + (size_t)(b * KP + k) * (NN * NN));
    const float4* gH = (const float4*)(ws + OFF_H + (size_t)b * (NN * HH));
    const float4* gW = (const float4*)(ws + OFF_WAUGT + (size_t)k * (HH * MM));

    // prefetch WaugT slab into registers (consumed after phase A)
    float4 pw0 = gW[tid], pw1 = gW[tid + 256], pw2 = gW[tid + 512], pw3 = gW[tid + 768];

    {
        float4* dA = (float4*)A_s;
        float4* dH = (float4*)H_s;
#pragma unroll
        for (int q = 0; q < 4; ++q) {
            dA[tid + q * 256] = gA[tid + q * 256];
            dH[tid + q * 256] = gH[tid + q * 256];
        }
    }
    __syncthreads();

    const int tx = tid & 15;   // f4 group (j in A, j in B)
    const int ty = tid >> 4;   // f4 group (h in A, m in B)

    // ---- phase A ----
    float4 o0 = {0,0,0,0}, o1 = {0,0,0,0}, o2 = {0,0,0,0}, o3 = {0,0,0,0};
    {
        const float4* A4 = (const float4*)A_s;
        const float4* H4 = (const float4*)H_s;
#pragma unroll 8
        for (int i = 0; i < NN; ++i) {
            float4 av = A4[i * 16 + tx];   // ug2[i][4tx..+3]  (j)
            float4 hv = H4[i * 16 + ty];   // h[i][4ty..+3]    (h)
            o0.x += av.x * hv.x; o0.y += av.y * hv.x; o0.z += av.z * hv.x; o0.w += av.w * hv.x;
            o1.x += av.x * hv.y; o1.y += av.y * hv.y; o1.z += av.z * hv.y; o1.w += av.w * hv.y;
            o2.x += av.x * hv.z; o2.y += av.y * hv.z; o2.z += av.z * hv.z; o2.w += av.w * hv.z;
            o3.x += av.x * hv.w; o3.y += av.y * hv.w; o3.z += av.z * hv.w; o3.w += av.w * hv.w;
        }
    }
    // T_s does not alias A_s/H_s: write before the barrier
    {
        float4* T4 = (float4*)T_s;
        T4[(4 * ty + 0) * 16 + tx] = o0;
        T4[(4 * ty + 1) * 16 + tx] = o1;
        T4[(4 * ty + 2) * 16 + tx] = o2;
        T4[(4 * ty + 3) * 16 + tx] = o3;
    }
    __syncthreads();           // everyone done reading A_s -> safe to overwrite with W

    {
        float4* W4 = (float4*)W_s;
        W4[tid]       = pw0;
        W4[tid + 256] = pw1;
        W4[tid + 512] = pw2;
        W4[tid + 768] = pw3;
    }
    __syncthreads();

    // ---- phase B ----
    float acc[4][4];
#pragma unroll
    for (int jq = 0; jq < 4; ++jq)
#pragma unroll
        for (int mq = 0; mq < 4; ++mq) acc[jq][mq] = 0.0f;
    {
        const float4* T4 = (const float4*)T_s;
        const float4* W4 = (const float4*)W_s;
#pragma unroll 8
        for (int hh = 0; hh < HH; ++hh) {
            float4 t4 = T4[hh * 16 + tx];  // T[h][4tx..+3]   (j)
            float4 w4 = W4[hh * 16 + ty];  // W[h][4ty..+3]   (m)
            acc[0][0] += t4.x * w4.x; acc[0][1] += t4.x * w4.y; acc[0][2] += t4.x * w4.z; acc[0][3] += t4.x * w4.w;
            acc[1][0] += t4.y * w4.x; acc[1][1] += t4.y * w4.y; acc[1][2] += t4.y * w4.z; acc[1][3] += t4.y * w4.w;
            acc[2][0] += t4.z * w4.x; acc[2][1] += t4.z * w4.y; acc[2][2] += t4.z * w4.z; acc[2][3] += t4.z * w4.w;
            acc[3][0] += t4.w * w4.x; acc[3][1] += t4.w * w4.y; acc[3][2] += t4.w * w4.z; acc[3][3] += t4.w * w4.w;
        }
    }

    float* mg = ws + OFF_M + (size_t)b * (NN * MM);
#pragma unroll
    for (int jq = 0; jq < 4; ++jq)
#pragma unroll
        for (int mq = 0; mq < 4; ++mq)
            atomicAdd(&mg[(4 * tx + jq) * MM + 4 * ty + mq], acc[jq][mq]);
}

// ============================================================
// GRU: 512 blocks, one node each (verified round-2 math).
// Reads m[node] from global, zeroes it for the next layer.
// ============================================================
__global__ __launch_bounds__(NTHR) void k_gru(
    const float* __restrict__ W_ih, const float* __restrict__ W_hh,
    const float* __restrict__ b_ih, const float* __restrict__ b_hh,
    float* __restrict__ ws)
{
    const int node = blockIdx.x;
    const int tid = threadIdx.x;

    __shared__ float mv[MM], hvs[HH];
    __shared__ float gi_s[3 * HH], gh_s[3 * HH];

    float* mg = ws + OFF_M + (size_t)node * MM;
    float* h  = ws + OFF_H;
    const float* valid = ws + OFF_VALID;

    if (tid < MM) {
        mv[tid]  = mg[tid];
        hvs[tid] = h[(size_t)node * HH + tid];
    }
    __syncthreads();
    if (tid < MM) mg[tid] = 0.0f;      // reset accumulator for next layer

    if (tid < 3 * HH) {
        const int x = tid;
        float gi = b_ih[x], gh = b_hh[x];
        const float4* wi = (const float4*)(W_ih + x * MM);
        const float4* wh = (const float4*)(W_hh + x * HH);
        const float4* m4 = (const float4*)mv;
        const float4* h4 = (const float4*)hvs;
#pragma unroll
        for (int c = 0; c < HH / 4; ++c) {
            float4 aw = wi[c], bw = wh[c];
            float4 mvv = m4[c], hvv = h4[c];
            gi += aw.x * mvv.x + aw.y * mvv.y + aw.z * mvv.z + aw.w * mvv.w;
            gh += bw.x * hvv.x + bw.y * hvv.y + bw.z * hvv.z + bw.w * hvv.w;
        }
        gi_s[x] = gi;
        gh_s[x] = gh;
    }
    __syncthreads();

    if (tid < HH) {
        float r = 1.0f / (1.0f + expf(-(gi_s[tid] + gh_s[tid])));
        float z = 1.0f / (1.0f + expf(-(gi_s[HH + tid] + gh_s[HH + tid])));
        float n = tanhf(gi_s[2 * HH + tid] + r * gh_s[2 * HH + tid]);
        float hn = (1.0f - z) * n + z * hvs[tid];
        h[(size_t)node * HH + tid] = hn * valid[node];
    }
}

// ============================================================
// readout (verified): 512 blocks, one node each.
// ============================================================
__global__ __launch_bounds__(NTHR) void k_readout(
    const float* __restrict__ Wi1, const float* __restrict__ bi1,
    const float* __restrict__ Wi2, const float* __restrict__ bi2,
    const float* __restrict__ Wj1, const float* __restrict__ bj1,
    const float* __restrict__ Wj2, const float* __restrict__ bj2,
    float* __restrict__ ws, float* __restrict__ out)
{
    __shared__ float cat[2 * HH];
    __shared__ float ih[RD], jh[RD];
    const float* h     = ws + OFF_H;
    const float* h0    = ws + OFF_H0;
    const float* valid = ws + OFF_VALID;
    int node = blockIdx.x, b = node >> 6, tid = threadIdx.x;

    if (tid < 2 * HH)
        cat[tid] = (tid < HH) ? h[(size_t)node * HH + tid]
                              : h0[(size_t)node * HH + (tid - HH)];
    __syncthreads();

    if (tid < RD) {
        float a = bi1[tid];
        for (int c = 0; c < 2 * HH; ++c) a += cat[c] * Wi1[c * RD + tid];
        ih[tid] = fmaxf(a, 0.0f);
        float bj = bj1[tid];
        for (int c = 0; c < HH; ++c) bj += cat[c] * Wj1[c * RD + tid];
        jh[tid] = fmaxf(bj, 0.0f);
    }
    __syncthreads();

    if (tid < TT) {
        float i2 = bi2[tid], j2 = bj2[tid];
        for (int u = 0; u < RD; ++u) {
            i2 += ih[u] * Wi2[u * TT + tid];
            j2 += jh[u] * Wj2[u * TT + tid];
        }
        float sig = 1.0f / (1.0f + expf(-i2));
        atomicAdd(&out[b * TT + tid], valid[node] * sig * j2);
    }
}

// ============================================================
extern "C" void kernel_launch(void* const* d_in, const int* in_sizes, int n_in,
                              void* d_out, int out_size, void* d_ws, size_t ws_size,
                              hipStream_t stream) {
    (void)in_sizes; (void)n_in; (void)out_size; (void)ws_size;
    const float* g    = (const float*)d_in[0];
    const float* h_in = (const float*)d_in[1];
    const float* e    = (const float*)d_in[2];
    const float* We1  = (const float*)d_in[3];
    const float* be1  = (const float*)d_in[4];
    const float* We2  = (const float*)d_in[5];
    const float* be2  = (const float*)d_in[6];
    const float* W_ih = (const float*)d_in[7];
    const float* W_hh = (const float*)d_in[8];
    const float* b_ih = (const float*)d_in[9];
    const float* b_hh = (const float*)d_in[10];
    const float* Wi1  = (const float*)d_in[11];
    const float* bi1  = (const float*)d_in[12];
    const float* Wi2  = (const float*)d_in[13];
    const float* bi2  = (const float*)d_in[14];
    const float* Wj1  = (const float*)d_in[15];
    const float* bj1  = (const float*)d_in[16];
    const float* Wj2  = (const float*)d_in[17];
    const float* bj2  = (const float*)d_in[18];
    float* out = (float*)d_out;
    float* ws  = (float*)d_ws;

    k_prep_edge<<<256, NTHR, 0, stream>>>(g, h_in, e, We1, be1, We2, be2, ws, out);
    for (int l = 0; l < NL; ++l) {
        k_fused_msg<<<BB * KP, NTHR, 0, stream>>>(ws);
        k_gru<<<NODES, NTHR, 0, stream>>>(W_ih, W_hh, b_ih, b_hh, ws);
    }
    k_readout<<<NODES, NTHR, 0, stream>>>(Wi1, bi1, Wi2, bi2, Wj1, bj1, Wj2, bj2, ws, out);
}